// Round 10
// baseline (540.860 us; speedup 1.0000x reference)
//
#include <hip/hip_runtime.h>
#include <stdint.h>

// ---------------------------------------------------------------------------
// LSH attention, B=4 S=2048 E=1024, fp32 in/out.
// GEMMs: bf16 MFMA "3K split packing" (A:[hi,hi,lo] B:[hi,lo,hi] => fp32-ish).
// r8: 4-phase pipelined cores verified on HW (519us, absmax 9.77e-4, 0 bank
// conflicts, FETCH 599->129MB).
// r9 changes (this kernel, resubmitted):
//  - proj: 128x128 tile / 256 thr / 64KB LDS -> 2 independent blocks/CU,
//    grid 1536 = exactly 6/CU (removes the 384-block 1.5-round tail and lets
//    co-resident blocks hide barrier/gate stalls; m97/m114 mechanism).
//  - softmax: float4/ushort4 vectorized contiguous per-thread chunks.
//  - scores/pv/pack/transpose unchanged (controls).
// ---------------------------------------------------------------------------

#define B_ 4
#define S_ 2048
#define E_ 1024
#define K3 3072
#define K6 6144

#define OFF_HHAT 0ULL
#define OFF_WHAT 50331648ULL
#define OFF_QHAT 69206016ULL
#define OFF_KHAT 119537664ULL
#define OFF_VT   169869312ULL
#define OFF_VHI  220200960ULL
#define OFF_VLO  236978176ULL
#define OFF_SC   0ULL
#define OFF_PHAT 69206016ULL

typedef __attribute__((ext_vector_type(8))) short bf16x8;
typedef __attribute__((ext_vector_type(4))) float f32x4;

__device__ __forceinline__ uint16_t f2bf(float x) {
    uint32_t u = __float_as_uint(x);
    uint32_t r = (u + 0x7fffu + ((u >> 16) & 1u)) >> 16;   // RNE
    return (uint16_t)r;
}
__device__ __forceinline__ float bf2f(uint16_t b) {
    return __uint_as_float(((uint32_t)b) << 16);
}

// ---------------------------------------------------------------------------
// pack: h -> Hhat [hi,hi,lo]; Wq/Wk/Wv -> What [hi,lo,hi]
// ---------------------------------------------------------------------------
__global__ void pack_inputs(const float* __restrict__ h,
                            const float* __restrict__ Wq, const float* __restrict__ Wk,
                            const float* __restrict__ Wv,
                            uint16_t* __restrict__ Hhat, uint16_t* __restrict__ What)
{
    int r = blockIdx.x;
    const float* src;
    uint16_t* dst;
    int pat;
    if (r < 8192) {
        src = h + (size_t)r * E_;
        dst = Hhat + (size_t)r * K3;
        pat = 0;
    } else {
        int w = r - 8192;
        int wz = w >> 10, wr = w & 1023;
        const float* W = (wz == 0) ? Wq : (wz == 1) ? Wk : Wv;
        src = W + (size_t)wr * E_;
        dst = What + ((size_t)wz * E_ + wr) * K3;
        pat = 1;
    }
    int c = threadIdx.x * 4;
    float4 x = *(const float4*)(src + c);
    float xs[4] = {x.x, x.y, x.z, x.w};
    uint16_t h4[4], l4[4];
#pragma unroll
    for (int i = 0; i < 4; ++i) {
        h4[i] = f2bf(xs[i]);
        l4[i] = f2bf(xs[i] - bf2f(h4[i]));
    }
    ushort4 hv = make_ushort4(h4[0], h4[1], h4[2], h4[3]);
    ushort4 lv = make_ushort4(l4[0], l4[1], l4[2], l4[3]);
    *(ushort4*)(dst + c) = hv;
    if (pat == 0) {
        *(ushort4*)(dst + E_ + c) = hv;
        *(ushort4*)(dst + 2 * E_ + c) = lv;
    } else {
        *(ushort4*)(dst + E_ + c) = lv;
        *(ushort4*)(dst + 2 * E_ + c) = hv;
    }
}

// ---------------------------------------------------------------------------
// 8-wave pipelined core (512 thr), tile BMT x 256 — used by scores (256) and
// pv (128). Verified r8: 0 bank conflicts, absmax 9.77e-4.
// ---------------------------------------------------------------------------
template<int BMT>
__device__ __forceinline__ void gemm_core256(const uint16_t* __restrict__ A,
                                             const uint16_t* __restrict__ Bm,
                                             int K, int tileM, int tileN,
                                             uint8_t* smem, f32x4 (*acc)[4])
{
    constexpr int MF     = BMT / 32;
    constexpr int MF2    = MF / 2;
    constexpr int A_HALF = BMT * 64;
    constexpr int BBASE  = 2 * A_HALF;
    constexpr int BUFSZ  = 2 * A_HALF + 32768;
    constexpr int CW_A   = BMT / 128;
    constexpr int GATE   = CW_A + 2;

    const int tid  = threadIdx.x;
    const int lane = tid & 63;
    const int wave = tid >> 6;
    const int waveM = wave >> 2;
    const int waveN = wave & 3;
    const int nT = K >> 6;

    const int srow = lane >> 2;
    const int g8   = ((lane & 3) ^ ((lane >> 5) << 1)) * 8;

    auto stageA = [&](uint8_t* bufW, int t, int h) {
#pragma unroll
        for (int cc = 0; cc < CW_A; ++cc) {
            const int c = wave * CW_A + cc;
            const uint16_t* src = A + (size_t)(tileM + c * 16 + srow) * K + t * 64 + h * 32 + g8;
            uint8_t* dst = bufW + h * A_HALF + c * 1024;
            __builtin_amdgcn_global_load_lds(
                (const __attribute__((address_space(1))) uint32_t*)src,
                (__attribute__((address_space(3))) uint32_t*)dst, 16, 0, 0);
        }
    };
    auto stageB = [&](uint8_t* bufW, int t, int h) {
#pragma unroll
        for (int cc = 0; cc < 2; ++cc) {
            const int c = wave * 2 + cc;
            const uint16_t* src = Bm + (size_t)(tileN + c * 16 + srow) * K + t * 64 + h * 32 + g8;
            uint8_t* dst = bufW + BBASE + h * 16384 + c * 1024;
            __builtin_amdgcn_global_load_lds(
                (const __attribute__((address_space(1))) uint32_t*)src,
                (__attribute__((address_space(3))) uint32_t*)dst, 16, 0, 0);
        }
    };

    stageA(smem, 0, 0); stageB(smem, 0, 0); stageA(smem, 0, 1); stageB(smem, 0, 1);
    asm volatile("s_waitcnt vmcnt(%0)" :: "i"(GATE) : "memory");
    __builtin_amdgcn_s_barrier();

    for (int t = 0; t < nT; ++t) {
        uint8_t* bufR = smem + (t & 1) * BUFSZ;
        uint8_t* bufW = smem + ((t & 1) ^ 1) * BUFSZ;
        const int tn = (t + 1 == nT) ? 0 : t + 1;
        bf16x8 bfrag[4];
#pragma unroll
        for (int p = 0; p < 4; ++p) {
            const int kh = p >> 1, mh = p & 1;
            if (mh == 0) {
#pragma unroll
                for (int n = 0; n < 4; ++n) {
                    int off = BBASE + kh * 16384 +
                              (waveN * 64 + n * 16 + (lane & 15)) * 64 + (lane >> 4) * 16;
                    off ^= ((off >> 9) & 1) << 5;
                    bfrag[n] = *(const bf16x8*)(bufR + off);
                }
            }
            bf16x8 afrag[MF2];
#pragma unroll
            for (int i = 0; i < MF2; ++i) {
                int off = kh * A_HALF +
                          (waveM * (BMT / 2) + (mh * MF2 + i) * 16 + (lane & 15)) * 64 +
                          (lane >> 4) * 16;
                off ^= ((off >> 9) & 1) << 5;
                afrag[i] = *(const bf16x8*)(bufR + off);
            }
            if (p == 0)      stageA(bufW, tn, 0);
            else if (p == 1) stageB(bufW, tn, 0);
            else if (p == 2) stageA(bufW, tn, 1);
            else             stageB(bufW, tn, 1);
            if (p == 1 || p == 3)
                asm volatile("s_waitcnt vmcnt(%0)" :: "i"(GATE) : "memory");
            __builtin_amdgcn_s_barrier();
            __builtin_amdgcn_s_setprio(1);
#pragma unroll
            for (int i = 0; i < MF2; ++i)
#pragma unroll
                for (int n = 0; n < 4; ++n)
                    acc[mh * MF2 + i][n] = __builtin_amdgcn_mfma_f32_16x16x32_bf16(
                        afrag[i], bfrag[n], acc[mh * MF2 + i][n], 0, 0, 0);
            __builtin_amdgcn_s_setprio(0);
            __builtin_amdgcn_s_barrier();
        }
    }
    asm volatile("s_waitcnt vmcnt(0)" ::: "memory");
    __builtin_amdgcn_s_barrier();
}

// ---------------------------------------------------------------------------
// 4-wave pipelined core (256 thr), tile 128x128, 64KB LDS
// -> 2 independent blocks/CU. Same 4-phase schedule, same swizzle (1KB/16-row
// chunk layout identical), same GATE=4 arithmetic (2 loads/stage/wave).
// ---------------------------------------------------------------------------
__device__ __forceinline__ void gemm_core128(const uint16_t* __restrict__ A,
                                             const uint16_t* __restrict__ Bm,
                                             int K, int tileM, int tileN,
                                             uint8_t* smem, f32x4 (*acc)[4])
{
    constexpr int A_HALF = 128 * 64;          // 8192 B per k-half
    constexpr int BBASE  = 2 * A_HALF;        // 16384
    constexpr int BUFSZ  = 4 * A_HALF;        // 32768 per dbuf slot
    constexpr int GATE   = 4;

    const int tid  = threadIdx.x;
    const int lane = tid & 63;
    const int wave = tid >> 6;                // 0..3
    const int waveM = wave >> 1;              // 0..1
    const int waveN = wave & 1;               // 0..1
    const int nT = K >> 6;

    const int srow = lane >> 2;
    const int g8   = ((lane & 3) ^ ((lane >> 5) << 1)) * 8;

    auto stageA = [&](uint8_t* bufW, int t, int h) {
#pragma unroll
        for (int cc = 0; cc < 2; ++cc) {
            const int c = wave * 2 + cc;      // 8 chunks x 16 rows = 128 rows
            const uint16_t* src = A + (size_t)(tileM + c * 16 + srow) * K + t * 64 + h * 32 + g8;
            uint8_t* dst = bufW + h * A_HALF + c * 1024;
            __builtin_amdgcn_global_load_lds(
                (const __attribute__((address_space(1))) uint32_t*)src,
                (__attribute__((address_space(3))) uint32_t*)dst, 16, 0, 0);
        }
    };
    auto stageB = [&](uint8_t* bufW, int t, int h) {
#pragma unroll
        for (int cc = 0; cc < 2; ++cc) {
            const int c = wave * 2 + cc;
            const uint16_t* src = Bm + (size_t)(tileN + c * 16 + srow) * K + t * 64 + h * 32 + g8;
            uint8_t* dst = bufW + BBASE + h * A_HALF + c * 1024;
            __builtin_amdgcn_global_load_lds(
                (const __attribute__((address_space(1))) uint32_t*)src,
                (__attribute__((address_space(3))) uint32_t*)dst, 16, 0, 0);
        }
    };

    stageA(smem, 0, 0); stageB(smem, 0, 0); stageA(smem, 0, 1); stageB(smem, 0, 1);
    asm volatile("s_waitcnt vmcnt(%0)" :: "i"(GATE) : "memory");
    __builtin_amdgcn_s_barrier();

    for (int t = 0; t < nT; ++t) {
        uint8_t* bufR = smem + (t & 1) * BUFSZ;
        uint8_t* bufW = smem + ((t & 1) ^ 1) * BUFSZ;
        const int tn = (t + 1 == nT) ? 0 : t + 1;
        bf16x8 bfrag[4];
#pragma unroll
        for (int p = 0; p < 4; ++p) {
            const int kh = p >> 1, mh = p & 1;
            if (mh == 0) {
#pragma unroll
                for (int n = 0; n < 4; ++n) {
                    int off = BBASE + kh * A_HALF +
                              (waveN * 64 + n * 16 + (lane & 15)) * 64 + (lane >> 4) * 16;
                    off ^= ((off >> 9) & 1) << 5;
                    bfrag[n] = *(const bf16x8*)(bufR + off);
                }
            }
            bf16x8 afrag[2];
#pragma unroll
            for (int i = 0; i < 2; ++i) {
                int off = kh * A_HALF +
                          (waveM * 64 + (mh * 2 + i) * 16 + (lane & 15)) * 64 +
                          (lane >> 4) * 16;
                off ^= ((off >> 9) & 1) << 5;
                afrag[i] = *(const bf16x8*)(bufR + off);
            }
            if (p == 0)      stageA(bufW, tn, 0);
            else if (p == 1) stageB(bufW, tn, 0);
            else if (p == 2) stageA(bufW, tn, 1);
            else             stageB(bufW, tn, 1);
            if (p == 1 || p == 3)
                asm volatile("s_waitcnt vmcnt(%0)" :: "i"(GATE) : "memory");
            __builtin_amdgcn_s_barrier();
            __builtin_amdgcn_s_setprio(1);
#pragma unroll
            for (int i = 0; i < 2; ++i)
#pragma unroll
                for (int n = 0; n < 4; ++n)
                    acc[mh * 2 + i][n] = __builtin_amdgcn_mfma_f32_16x16x32_bf16(
                        afrag[i], bfrag[n], acc[mh * 2 + i][n], 0, 0, 0);
            __builtin_amdgcn_s_setprio(0);
            __builtin_amdgcn_s_barrier();
        }
    }
    asm volatile("s_waitcnt vmcnt(0)" ::: "memory");
    __builtin_amdgcn_s_barrier();
}

// ---------------------------------------------------------------------------
// QKV projection: 128x128 tiles, 256 thr, 2 blocks/CU.
// grid 1536 = 64(M) * 8(N) * 3(z) = 6/CU exactly; XCD swizzle 1536 = 8*192.
// ---------------------------------------------------------------------------
__global__ __launch_bounds__(256, 2) void gemm_proj2(
    const uint16_t* __restrict__ Hhat, const uint16_t* __restrict__ What,
    const float* __restrict__ bq, const float* __restrict__ bk, const float* __restrict__ bv,
    uint16_t* __restrict__ Qhat, uint16_t* __restrict__ Khat,
    uint16_t* __restrict__ Vhi, uint16_t* __restrict__ Vlo)
{
    __shared__ __align__(16) uint8_t smem[65536];
    const int f = blockIdx.x;
    const int swz = (f & 7) * 192 + (f >> 3);     // 1536 = 8*192
    const int z = swz >> 9;                       // /512
    const int rm = swz & 511;
    const int tileM = (rm >> 3) * 128, tileN = (rm & 7) * 128;

    f32x4 acc[4][4];
#pragma unroll
    for (int i = 0; i < 4; ++i)
#pragma unroll
        for (int j = 0; j < 4; ++j) acc[i][j] = (f32x4){0.f, 0.f, 0.f, 0.f};

    gemm_core128(Hhat, What + (size_t)z * E_ * K3, K3, tileM, tileN, smem, acc);

    const float* bias = (z == 0) ? bq : (z == 1) ? bk : bv;
    const int lane = threadIdx.x & 63, wave = threadIdx.x >> 6;
    const int waveM = wave >> 1, waveN = wave & 1;
#pragma unroll
    for (int i = 0; i < 4; ++i) {
#pragma unroll
        for (int j = 0; j < 4; ++j) {
            int col = tileN + waveN * 64 + j * 16 + (lane & 15);
            float bc = bias[col];
#pragma unroll
            for (int r = 0; r < 4; ++r) {
                int row = tileM + waveM * 64 + i * 16 + (lane >> 4) * 4 + r;
                float v = acc[i][j][r] + bc;
                uint16_t hi = f2bf(v);
                uint16_t lo = f2bf(v - bf2f(hi));
                if (z == 0) {
                    size_t base = (size_t)row * K3;
                    Qhat[base + col] = hi; Qhat[base + E_ + col] = hi; Qhat[base + 2 * E_ + col] = lo;
                } else if (z == 1) {
                    size_t base = (size_t)row * K3;
                    Khat[base + col] = hi; Khat[base + E_ + col] = lo; Khat[base + 2 * E_ + col] = hi;
                } else {
                    size_t base = (size_t)row * E_ + col;
                    Vhi[base] = hi; Vlo[base] = lo;
                }
            }
        }
    }
}

// ---------------------------------------------------------------------------
// scores = Q K^T / 32 : 256x256 tiles, grid 256 = 8(N)*8(M)*4(b)  [unchanged]
// ---------------------------------------------------------------------------
__global__ __launch_bounds__(512, 2) void gemm_scores(
    const uint16_t* __restrict__ Qh, const uint16_t* __restrict__ Kh, float* __restrict__ C)
{
    __shared__ __align__(16) uint8_t smem[131072];
    const int f = blockIdx.x;
    const int swz = (f & 7) * 32 + (f >> 3);
    const int z = swz >> 6;
    const int rm = swz & 63;
    const int tileM = (rm >> 3) * 256, tileN = (rm & 7) * 256;

    f32x4 acc[8][4];
#pragma unroll
    for (int i = 0; i < 8; ++i)
#pragma unroll
        for (int j = 0; j < 4; ++j) acc[i][j] = (f32x4){0.f, 0.f, 0.f, 0.f};

    gemm_core256<256>(Qh + (size_t)z * S_ * K3, Kh + (size_t)z * S_ * K3, K3,
                      tileM, tileN, smem, acc);

    float* Cb = C + (size_t)z * S_ * S_;
    const int lane = threadIdx.x & 63, wave = threadIdx.x >> 6;
    const int waveM = wave >> 2, waveN = wave & 3;
#pragma unroll
    for (int i = 0; i < 8; ++i)
#pragma unroll
        for (int j = 0; j < 4; ++j) {
            int col = tileN + waveN * 64 + j * 16 + (lane & 15);
#pragma unroll
            for (int r = 0; r < 4; ++r) {
                int row = tileM + waveM * 128 + i * 16 + (lane >> 4) * 4 + r;
                Cb[(size_t)row * S_ + col] = acc[i][j][r] * (1.0f / 32.0f);
            }
        }
}

// ---------------------------------------------------------------------------
// context = P V : 128x256 tiles, grid 256 = 4(N)*16(M)*4(b)  [unchanged]
// ---------------------------------------------------------------------------
__global__ __launch_bounds__(512, 2) void gemm_pv(
    const uint16_t* __restrict__ Ph, const uint16_t* __restrict__ Vt, float* __restrict__ C)
{
    __shared__ __align__(16) uint8_t smem[98304];
    const int f = blockIdx.x;
    const int swz = (f & 7) * 32 + (f >> 3);
    const int z = swz >> 6;
    const int rm = swz & 63;
    const int tileM = (rm >> 2) * 128, tileN = (rm & 3) * 256;

    f32x4 acc[4][4];
#pragma unroll
    for (int i = 0; i < 4; ++i)
#pragma unroll
        for (int j = 0; j < 4; ++j) acc[i][j] = (f32x4){0.f, 0.f, 0.f, 0.f};

    gemm_core256<128>(Ph + (size_t)z * S_ * K6, Vt + (size_t)z * E_ * K6, K6,
                      tileM, tileN, smem, acc);

    float* Cb = C + (size_t)z * S_ * E_;
    const int lane = threadIdx.x & 63, wave = threadIdx.x >> 6;
    const int waveM = wave >> 2, waveN = wave & 3;
#pragma unroll
    for (int i = 0; i < 4; ++i)
#pragma unroll
        for (int j = 0; j < 4; ++j) {
            int col = tileN + waveN * 64 + j * 16 + (lane & 15);
#pragma unroll
            for (int r = 0; r < 4; ++r) {
                int row = tileM + waveM * 64 + i * 16 + (lane >> 4) * 4 + r;
                Cb[(size_t)row * E_ + col] = acc[i][j][r];
            }
        }
}

// ---------------------------------------------------------------------------
// V transpose  [unchanged]
// ---------------------------------------------------------------------------
__global__ void transpose_v(const uint16_t* __restrict__ Vhi, const uint16_t* __restrict__ Vlo,
                            uint16_t* __restrict__ Vt)
{
    __shared__ uint16_t sh[32][33];
    __shared__ uint16_t sl[32][33];
    const int b = blockIdx.z;
    const int t0 = blockIdx.x * 32, e0 = blockIdx.y * 32;
    const int tx = threadIdx.x & 31, ty = threadIdx.x >> 5;
    for (int r = ty; r < 32; r += 8) {
        size_t src = ((size_t)b * S_ + t0 + r) * E_ + e0 + tx;
        sh[r][tx] = Vhi[src];
        sl[r][tx] = Vlo[src];
    }
    __syncthreads();
    for (int r = ty; r < 32; r += 8) {
        size_t base = ((size_t)b * E_ + e0 + r) * (size_t)K6;
        uint16_t h = sh[tx][r], l = sl[tx][r];
        Vt[base + t0 + tx] = h;
        Vt[base + S_ + t0 + tx] = l;
        Vt[base + 2 * S_ + t0 + tx] = h;
    }
}

// ---------------------------------------------------------------------------
// masked softmax + split-pack P. r9: vectorized — each thread owns 8
// CONTIGUOUS t (float4 x2 loads, ushort4 x2 stores per plane).
// ---------------------------------------------------------------------------
__global__ __launch_bounds__(256) void softmax_split(const float* __restrict__ scores,
                                                     const int* __restrict__ buckets,
                                                     uint16_t* __restrict__ Phat)
{
    const int s = blockIdx.x, b = blockIdx.y;
    const float* row = scores + ((size_t)b * S_ + s) * S_;
    const int* brow = buckets + b * S_;
    const int myb = brow[s];
    const int tid = threadIdx.x;
    const int lane = tid & 63, wave = tid >> 6;
    const int t0 = tid * 8;

    float4 x0 = *(const float4*)(row + t0);
    float4 x1 = *(const float4*)(row + t0 + 4);
    int4 q0 = *(const int4*)(brow + t0);
    int4 q1 = *(const int4*)(brow + t0 + 4);

    float vals[8] = {x0.x, x0.y, x0.z, x0.w, x1.x, x1.y, x1.z, x1.w};
    int bks[8] = {q0.x, q0.y, q0.z, q0.w, q1.x, q1.y, q1.z, q1.w};
    float m = -1e30f;
#pragma unroll
    for (int i = 0; i < 8; ++i) {
        float x = (bks[i] == myb) ? vals[i] : -1e30f;
        vals[i] = x;
        m = fmaxf(m, x);
    }
#pragma unroll
    for (int off = 32; off > 0; off >>= 1) m = fmaxf(m, __shfl_xor(m, off));
    __shared__ float red[8];
    if (lane == 0) red[wave] = m;
    __syncthreads();
    m = fmaxf(fmaxf(red[0], red[1]), fmaxf(red[2], red[3]));

    float sum = 0.f;
#pragma unroll
    for (int i = 0; i < 8; ++i) {
        float p = __expf(vals[i] - m);
        vals[i] = p;
        sum += p;
    }
#pragma unroll
    for (int off = 32; off > 0; off >>= 1) sum += __shfl_xor(sum, off);
    if (lane == 0) red[4 + wave] = sum;
    __syncthreads();
    sum = red[4] + red[5] + red[6] + red[7];
    float inv = 1.f / sum;

    uint16_t hi[8], lo[8];
#pragma unroll
    for (int i = 0; i < 8; ++i) {
        float p = vals[i] * inv;
        hi[i] = f2bf(p);
        lo[i] = f2bf(p - bf2f(hi[i]));
    }
    ushort4 h0 = make_ushort4(hi[0], hi[1], hi[2], hi[3]);
    ushort4 h1 = make_ushort4(hi[4], hi[5], hi[6], hi[7]);
    ushort4 l0 = make_ushort4(lo[0], lo[1], lo[2], lo[3]);
    ushort4 l1 = make_ushort4(lo[4], lo[5], lo[6], lo[7]);

    size_t base = ((size_t)b * S_ + s) * (size_t)K6;
    *(ushort4*)(Phat + base + t0)            = h0;
    *(ushort4*)(Phat + base + t0 + 4)        = h1;
    *(ushort4*)(Phat + base + S_ + t0)       = h0;
    *(ushort4*)(Phat + base + S_ + t0 + 4)   = h1;
    *(ushort4*)(Phat + base + 2 * S_ + t0)     = l0;
    *(ushort4*)(Phat + base + 2 * S_ + t0 + 4) = l1;
}

// ---------------------------------------------------------------------------
extern "C" void kernel_launch(void* const* d_in, const int* in_sizes, int n_in,
                              void* d_out, int out_size, void* d_ws, size_t ws_size,
                              hipStream_t stream)
{
    const float* h  = (const float*)d_in[0];
    const int*   hb = (const int*)d_in[1];
    const float* Wq = (const float*)d_in[2];
    const float* bq = (const float*)d_in[3];
    const float* Wk = (const float*)d_in[4];
    const float* bk = (const float*)d_in[5];
    const float* Wv = (const float*)d_in[6];
    const float* bv = (const float*)d_in[7];
    float* out = (float*)d_out;
    uint8_t* ws = (uint8_t*)d_ws;

    uint16_t* Hhat = (uint16_t*)(ws + OFF_HHAT);
    uint16_t* What = (uint16_t*)(ws + OFF_WHAT);
    uint16_t* Qhat = (uint16_t*)(ws + OFF_QHAT);
    uint16_t* Khat = (uint16_t*)(ws + OFF_KHAT);
    uint16_t* Vt   = (uint16_t*)(ws + OFF_VT);
    uint16_t* Vhi  = (uint16_t*)(ws + OFF_VHI);
    uint16_t* Vlo  = (uint16_t*)(ws + OFF_VLO);
    float*    sc   = (float*)(ws + OFF_SC);
    uint16_t* Phat = (uint16_t*)(ws + OFF_PHAT);

    pack_inputs<<<dim3(11264), 256, 0, stream>>>(h, Wq, Wk, Wv, Hhat, What);
    gemm_proj2<<<dim3(1536), 256, 0, stream>>>(Hhat, What, bq, bk, bv, Qhat, Khat, Vhi, Vlo);
    transpose_v<<<dim3(64, 32, 4), 256, 0, stream>>>(Vhi, Vlo, Vt);
    gemm_scores<<<dim3(256), 512, 0, stream>>>(Qhat, Khat, sc);
    softmax_split<<<dim3(S_, B_), 256, 0, stream>>>(sc, hb, Phat);
    gemm_pv<<<dim3(256), 512, 0, stream>>>(Phat, Vt, out);
}

// Round 13
// 525.347 us; speedup vs baseline: 1.0295x; 1.0295x over previous
//
#include <hip/hip_runtime.h>
#include <stdint.h>

// ---------------------------------------------------------------------------
// LSH attention, B=4 S=2048 E=1024, fp32 in/out.
// GEMMs: bf16 MFMA "3K split packing" (A:[hi,hi,lo] B:[hi,lo,hi] => fp32-ish).
// r8 (HW-verified): 4-phase pipelined 256-tile cores, 519us, absmax 9.77e-4,
//   0 bank conflicts. proj=203us @ MfmaUtil 32%, ~960cyc/phase overhead.
// r9 (HW-verified): 128-tile proj for 2 blocks/CU REGRESSED (244us) ->
//   limiter is per-phase overhead, not occupancy.
// r12 (this, resubmitted): merge 4 phases -> 2 phases per K-tile (kh only):
//   barriers/tile 8->4, MFMA/phase 2x, same gates (vmcnt(GATE) per phase,
//   GATE=CW_A+2, uniform counts), same swizzle, same per-acc MFMA order
//   (kh0 then kh1 per tile) => bit-identical numerics. proj on 256x256
//   grid 384. Vectorized softmax kept (r10-verified).
// ---------------------------------------------------------------------------

#define B_ 4
#define S_ 2048
#define E_ 1024
#define K3 3072
#define K6 6144

#define OFF_HHAT 0ULL
#define OFF_WHAT 50331648ULL
#define OFF_QHAT 69206016ULL
#define OFF_KHAT 119537664ULL
#define OFF_VT   169869312ULL
#define OFF_VHI  220200960ULL
#define OFF_VLO  236978176ULL
#define OFF_SC   0ULL
#define OFF_PHAT 69206016ULL

typedef __attribute__((ext_vector_type(8))) short bf16x8;
typedef __attribute__((ext_vector_type(4))) float f32x4;

__device__ __forceinline__ uint16_t f2bf(float x) {
    uint32_t u = __float_as_uint(x);
    uint32_t r = (u + 0x7fffu + ((u >> 16) & 1u)) >> 16;   // RNE
    return (uint16_t)r;
}
__device__ __forceinline__ float bf2f(uint16_t b) {
    return __uint_as_float(((uint32_t)b) << 16);
}

// ---------------------------------------------------------------------------
// pack: h -> Hhat [hi,hi,lo]; Wq/Wk/Wv -> What [hi,lo,hi]
// ---------------------------------------------------------------------------
__global__ void pack_inputs(const float* __restrict__ h,
                            const float* __restrict__ Wq, const float* __restrict__ Wk,
                            const float* __restrict__ Wv,
                            uint16_t* __restrict__ Hhat, uint16_t* __restrict__ What)
{
    int r = blockIdx.x;
    const float* src;
    uint16_t* dst;
    int pat;
    if (r < 8192) {
        src = h + (size_t)r * E_;
        dst = Hhat + (size_t)r * K3;
        pat = 0;
    } else {
        int w = r - 8192;
        int wz = w >> 10, wr = w & 1023;
        const float* W = (wz == 0) ? Wq : (wz == 1) ? Wk : Wv;
        src = W + (size_t)wr * E_;
        dst = What + ((size_t)wz * E_ + wr) * K3;
        pat = 1;
    }
    int c = threadIdx.x * 4;
    float4 x = *(const float4*)(src + c);
    float xs[4] = {x.x, x.y, x.z, x.w};
    uint16_t h4[4], l4[4];
#pragma unroll
    for (int i = 0; i < 4; ++i) {
        h4[i] = f2bf(xs[i]);
        l4[i] = f2bf(xs[i] - bf2f(h4[i]));
    }
    ushort4 hv = make_ushort4(h4[0], h4[1], h4[2], h4[3]);
    ushort4 lv = make_ushort4(l4[0], l4[1], l4[2], l4[3]);
    *(ushort4*)(dst + c) = hv;
    if (pat == 0) {
        *(ushort4*)(dst + E_ + c) = hv;
        *(ushort4*)(dst + 2 * E_ + c) = lv;
    } else {
        *(ushort4*)(dst + E_ + c) = lv;
        *(ushort4*)(dst + 2 * E_ + c) = hv;
    }
}

// ---------------------------------------------------------------------------
// 8-wave pipelined core (512 thr), tile BMT x 256, BK=64.
// 2 phases per K-tile (phase = kh). Per phase: read bfrag[4]+afrag[MF]
// for kh, stage one half-pair of tile t+1, vmcnt(GATE), barrier, MFMA (4*MF),
// barrier. GATE = CW_A+2 (one half-pair in flight after the wait).
// LDS layout/swizzle identical to the r8-verified version.
// ---------------------------------------------------------------------------
template<int BMT>
__device__ __forceinline__ void gemm_core256(const uint16_t* __restrict__ A,
                                             const uint16_t* __restrict__ Bm,
                                             int K, int tileM, int tileN,
                                             uint8_t* smem, f32x4 (*acc)[4])
{
    constexpr int MF     = BMT / 32;          // m-frags per wave
    constexpr int A_HALF = BMT * 64;          // bytes per A k-half
    constexpr int BBASE  = 2 * A_HALF;
    constexpr int BUFSZ  = 2 * A_HALF + 32768;
    constexpr int CW_A   = BMT / 128;         // A gload_lds calls/wave/half
    constexpr int GATE   = CW_A + 2;

    const int tid  = threadIdx.x;
    const int lane = tid & 63;
    const int wave = tid >> 6;
    const int waveM = wave >> 2;
    const int waveN = wave & 3;
    const int nT = K >> 6;

    const int srow = lane >> 2;
    const int g8   = ((lane & 3) ^ ((lane >> 5) << 1)) * 8;

    auto stageA = [&](uint8_t* bufW, int t, int h) {
#pragma unroll
        for (int cc = 0; cc < CW_A; ++cc) {
            const int c = wave * CW_A + cc;
            const uint16_t* src = A + (size_t)(tileM + c * 16 + srow) * K + t * 64 + h * 32 + g8;
            uint8_t* dst = bufW + h * A_HALF + c * 1024;
            __builtin_amdgcn_global_load_lds(
                (const __attribute__((address_space(1))) uint32_t*)src,
                (__attribute__((address_space(3))) uint32_t*)dst, 16, 0, 0);
        }
    };
    auto stageB = [&](uint8_t* bufW, int t, int h) {
#pragma unroll
        for (int cc = 0; cc < 2; ++cc) {
            const int c = wave * 2 + cc;
            const uint16_t* src = Bm + (size_t)(tileN + c * 16 + srow) * K + t * 64 + h * 32 + g8;
            uint8_t* dst = bufW + BBASE + h * 16384 + c * 1024;
            __builtin_amdgcn_global_load_lds(
                (const __attribute__((address_space(1))) uint32_t*)src,
                (__attribute__((address_space(3))) uint32_t*)dst, 16, 0, 0);
        }
    };

    // prologue: stage tile 0 fully; wait for its k0 half-pair
    stageA(smem, 0, 0); stageB(smem, 0, 0); stageA(smem, 0, 1); stageB(smem, 0, 1);
    asm volatile("s_waitcnt vmcnt(%0)" :: "i"(GATE) : "memory");
    __builtin_amdgcn_s_barrier();

    for (int t = 0; t < nT; ++t) {
        uint8_t* bufR = smem + (t & 1) * BUFSZ;
        uint8_t* bufW = smem + ((t & 1) ^ 1) * BUFSZ;
        const int tn = (t + 1 == nT) ? 0 : t + 1;   // dummy wrap on last tile
#pragma unroll
        for (int kh = 0; kh < 2; ++kh) {
            bf16x8 bfrag[4];
#pragma unroll
            for (int n = 0; n < 4; ++n) {
                int off = BBASE + kh * 16384 +
                          (waveN * 64 + n * 16 + (lane & 15)) * 64 + (lane >> 4) * 16;
                off ^= ((off >> 9) & 1) << 5;
                bfrag[n] = *(const bf16x8*)(bufR + off);
            }
            bf16x8 afrag[MF];
#pragma unroll
            for (int m = 0; m < MF; ++m) {
                int off = kh * A_HALF +
                          (waveM * (BMT / 2) + m * 16 + (lane & 15)) * 64 +
                          (lane >> 4) * 16;
                off ^= ((off >> 9) & 1) << 5;
                afrag[m] = *(const bf16x8*)(bufR + off);
            }
            // stage one half-pair of tile t+1
            stageA(bufW, tn, kh);
            stageB(bufW, tn, kh);
            asm volatile("s_waitcnt vmcnt(%0)" :: "i"(GATE) : "memory");
            __builtin_amdgcn_s_barrier();
            __builtin_amdgcn_s_setprio(1);
#pragma unroll
            for (int m = 0; m < MF; ++m)
#pragma unroll
                for (int n = 0; n < 4; ++n)
                    acc[m][n] = __builtin_amdgcn_mfma_f32_16x16x32_bf16(
                        afrag[m], bfrag[n], acc[m][n], 0, 0, 0);
            __builtin_amdgcn_s_setprio(0);
            __builtin_amdgcn_s_barrier();
        }
    }
    // drain dummy-wrap stages before epilogue / endpgm
    asm volatile("s_waitcnt vmcnt(0)" ::: "memory");
    __builtin_amdgcn_s_barrier();
}

// ---------------------------------------------------------------------------
// QKV projection: 256x256 tiles, grid 384 = 4(N)*32(M)*3(z), swz 384=8*48.
// ---------------------------------------------------------------------------
__global__ __launch_bounds__(512, 2) void gemm_proj2(
    const uint16_t* __restrict__ Hhat, const uint16_t* __restrict__ What,
    const float* __restrict__ bq, const float* __restrict__ bk, const float* __restrict__ bv,
    uint16_t* __restrict__ Qhat, uint16_t* __restrict__ Khat,
    uint16_t* __restrict__ Vhi, uint16_t* __restrict__ Vlo)
{
    __shared__ __align__(16) uint8_t smem[131072];
    const int f = blockIdx.x;
    const int swz = (f & 7) * 48 + (f >> 3);
    const int z = swz >> 7;
    const int rm = swz & 127;
    const int tileM = (rm >> 2) * 256, tileN = (rm & 3) * 256;

    f32x4 acc[8][4];
#pragma unroll
    for (int i = 0; i < 8; ++i)
#pragma unroll
        for (int j = 0; j < 4; ++j) acc[i][j] = (f32x4){0.f, 0.f, 0.f, 0.f};

    gemm_core256<256>(Hhat, What + (size_t)z * E_ * K3, K3, tileM, tileN, smem, acc);

    const float* bias = (z == 0) ? bq : (z == 1) ? bk : bv;
    const int lane = threadIdx.x & 63, wave = threadIdx.x >> 6;
    const int waveM = wave >> 2, waveN = wave & 3;
#pragma unroll
    for (int i = 0; i < 8; ++i) {
#pragma unroll
        for (int j = 0; j < 4; ++j) {
            int col = tileN + waveN * 64 + j * 16 + (lane & 15);
            float bc = bias[col];
#pragma unroll
            for (int r = 0; r < 4; ++r) {
                int row = tileM + waveM * 128 + i * 16 + (lane >> 4) * 4 + r;
                float v = acc[i][j][r] + bc;
                uint16_t hi = f2bf(v);
                uint16_t lo = f2bf(v - bf2f(hi));
                if (z == 0) {
                    size_t base = (size_t)row * K3;
                    Qhat[base + col] = hi; Qhat[base + E_ + col] = hi; Qhat[base + 2 * E_ + col] = lo;
                } else if (z == 1) {
                    size_t base = (size_t)row * K3;
                    Khat[base + col] = hi; Khat[base + E_ + col] = lo; Khat[base + 2 * E_ + col] = hi;
                } else {
                    size_t base = (size_t)row * E_ + col;
                    Vhi[base] = hi; Vlo[base] = lo;
                }
            }
        }
    }
}

// ---------------------------------------------------------------------------
// scores = Q K^T / 32 : 256x256 tiles, grid 256 = 8(N)*8(M)*4(b)
// ---------------------------------------------------------------------------
__global__ __launch_bounds__(512, 2) void gemm_scores(
    const uint16_t* __restrict__ Qh, const uint16_t* __restrict__ Kh, float* __restrict__ C)
{
    __shared__ __align__(16) uint8_t smem[131072];
    const int f = blockIdx.x;
    const int swz = (f & 7) * 32 + (f >> 3);
    const int z = swz >> 6;
    const int rm = swz & 63;
    const int tileM = (rm >> 3) * 256, tileN = (rm & 7) * 256;

    f32x4 acc[8][4];
#pragma unroll
    for (int i = 0; i < 8; ++i)
#pragma unroll
        for (int j = 0; j < 4; ++j) acc[i][j] = (f32x4){0.f, 0.f, 0.f, 0.f};

    gemm_core256<256>(Qh + (size_t)z * S_ * K3, Kh + (size_t)z * S_ * K3, K3,
                      tileM, tileN, smem, acc);

    float* Cb = C + (size_t)z * S_ * S_;
    const int lane = threadIdx.x & 63, wave = threadIdx.x >> 6;
    const int waveM = wave >> 2, waveN = wave & 3;
#pragma unroll
    for (int i = 0; i < 8; ++i)
#pragma unroll
        for (int j = 0; j < 4; ++j) {
            int col = tileN + waveN * 64 + j * 16 + (lane & 15);
#pragma unroll
            for (int r = 0; r < 4; ++r) {
                int row = tileM + waveM * 128 + i * 16 + (lane >> 4) * 4 + r;
                Cb[(size_t)row * S_ + col] = acc[i][j][r] * (1.0f / 32.0f);
            }
        }
}

// ---------------------------------------------------------------------------
// context = P V : 128x256 tiles, grid 256 = 4(N)*16(M)*4(b)
// ---------------------------------------------------------------------------
__global__ __launch_bounds__(512, 2) void gemm_pv(
    const uint16_t* __restrict__ Ph, const uint16_t* __restrict__ Vt, float* __restrict__ C)
{
    __shared__ __align__(16) uint8_t smem[98304];
    const int f = blockIdx.x;
    const int swz = (f & 7) * 32 + (f >> 3);
    const int z = swz >> 6;
    const int rm = swz & 63;
    const int tileM = (rm >> 2) * 128, tileN = (rm & 3) * 256;

    f32x4 acc[4][4];
#pragma unroll
    for (int i = 0; i < 4; ++i)
#pragma unroll
        for (int j = 0; j < 4; ++j) acc[i][j] = (f32x4){0.f, 0.f, 0.f, 0.f};

    gemm_core256<128>(Ph + (size_t)z * S_ * K6, Vt + (size_t)z * E_ * K6, K6,
                      tileM, tileN, smem, acc);

    float* Cb = C + (size_t)z * S_ * E_;
    const int lane = threadIdx.x & 63, wave = threadIdx.x >> 6;
    const int waveM = wave >> 2, waveN = wave & 3;
#pragma unroll
    for (int i = 0; i < 4; ++i)
#pragma unroll
        for (int j = 0; j < 4; ++j) {
            int col = tileN + waveN * 64 + j * 16 + (lane & 15);
#pragma unroll
            for (int r = 0; r < 4; ++r) {
                int row = tileM + waveM * 64 + i * 16 + (lane >> 4) * 4 + r;
                Cb[(size_t)row * E_ + col] = acc[i][j][r];
            }
        }
}

// ---------------------------------------------------------------------------
// V transpose  [unchanged]
// ---------------------------------------------------------------------------
__global__ void transpose_v(const uint16_t* __restrict__ Vhi, const uint16_t* __restrict__ Vlo,
                            uint16_t* __restrict__ Vt)
{
    __shared__ uint16_t sh[32][33];
    __shared__ uint16_t sl[32][33];
    const int b = blockIdx.z;
    const int t0 = blockIdx.x * 32, e0 = blockIdx.y * 32;
    const int tx = threadIdx.x & 31, ty = threadIdx.x >> 5;
    for (int r = ty; r < 32; r += 8) {
        size_t src = ((size_t)b * S_ + t0 + r) * E_ + e0 + tx;
        sh[r][tx] = Vhi[src];
        sl[r][tx] = Vlo[src];
    }
    __syncthreads();
    for (int r = ty; r < 32; r += 8) {
        size_t base = ((size_t)b * E_ + e0 + r) * (size_t)K6;
        uint16_t h = sh[tx][r], l = sl[tx][r];
        Vt[base + t0 + tx] = h;
        Vt[base + S_ + t0 + tx] = l;
        Vt[base + 2 * S_ + t0 + tx] = h;
    }
}

// ---------------------------------------------------------------------------
// masked softmax + split-pack P (vectorized, r10-verified)
// ---------------------------------------------------------------------------
__global__ __launch_bounds__(256) void softmax_split(const float* __restrict__ scores,
                                                     const int* __restrict__ buckets,
                                                     uint16_t* __restrict__ Phat)
{
    const int s = blockIdx.x, b = blockIdx.y;
    const float* row = scores + ((size_t)b * S_ + s) * S_;
    const int* brow = buckets + b * S_;
    const int myb = brow[s];
    const int tid = threadIdx.x;
    const int lane = tid & 63, wave = tid >> 6;
    const int t0 = tid * 8;

    float4 x0 = *(const float4*)(row + t0);
    float4 x1 = *(const float4*)(row + t0 + 4);
    int4 q0 = *(const int4*)(brow + t0);
    int4 q1 = *(const int4*)(brow + t0 + 4);

    float vals[8] = {x0.x, x0.y, x0.z, x0.w, x1.x, x1.y, x1.z, x1.w};
    int bks[8] = {q0.x, q0.y, q0.z, q0.w, q1.x, q1.y, q1.z, q1.w};
    float m = -1e30f;
#pragma unroll
    for (int i = 0; i < 8; ++i) {
        float x = (bks[i] == myb) ? vals[i] : -1e30f;
        vals[i] = x;
        m = fmaxf(m, x);
    }
#pragma unroll
    for (int off = 32; off > 0; off >>= 1) m = fmaxf(m, __shfl_xor(m, off));
    __shared__ float red[8];
    if (lane == 0) red[wave] = m;
    __syncthreads();
    m = fmaxf(fmaxf(red[0], red[1]), fmaxf(red[2], red[3]));

    float sum = 0.f;
#pragma unroll
    for (int i = 0; i < 8; ++i) {
        float p = __expf(vals[i] - m);
        vals[i] = p;
        sum += p;
    }
#pragma unroll
    for (int off = 32; off > 0; off >>= 1) sum += __shfl_xor(sum, off);
    if (lane == 0) red[4 + wave] = sum;
    __syncthreads();
    sum = red[4] + red[5] + red[6] + red[7];
    float inv = 1.f / sum;

    uint16_t hi[8], lo[8];
#pragma unroll
    for (int i = 0; i < 8; ++i) {
        float p = vals[i] * inv;
        hi[i] = f2bf(p);
        lo[i] = f2bf(p - bf2f(hi[i]));
    }
    ushort4 h0 = make_ushort4(hi[0], hi[1], hi[2], hi[3]);
    ushort4 h1 = make_ushort4(hi[4], hi[5], hi[6], hi[7]);
    ushort4 l0 = make_ushort4(lo[0], lo[1], lo[2], lo[3]);
    ushort4 l1 = make_ushort4(lo[4], lo[5], lo[6], lo[7]);

    size_t base = ((size_t)b * S_ + s) * (size_t)K6;
    *(ushort4*)(Phat + base + t0)            = h0;
    *(ushort4*)(Phat + base + t0 + 4)        = h1;
    *(ushort4*)(Phat + base + S_ + t0)       = h0;
    *(ushort4*)(Phat + base + S_ + t0 + 4)   = h1;
    *(ushort4*)(Phat + base + 2 * S_ + t0)     = l0;
    *(ushort4*)(Phat + base + 2 * S_ + t0 + 4) = l1;
}

// ---------------------------------------------------------------------------
extern "C" void kernel_launch(void* const* d_in, const int* in_sizes, int n_in,
                              void* d_out, int out_size, void* d_ws, size_t ws_size,
                              hipStream_t stream)
{
    const float* h  = (const float*)d_in[0];
    const int*   hb = (const int*)d_in[1];
    const float* Wq = (const float*)d_in[2];
    const float* bq = (const float*)d_in[3];
    const float* Wk = (const float*)d_in[4];
    const float* bk = (const float*)d_in[5];
    const float* Wv = (const float*)d_in[6];
    const float* bv = (const float*)d_in[7];
    float* out = (float*)d_out;
    uint8_t* ws = (uint8_t*)d_ws;

    uint16_t* Hhat = (uint16_t*)(ws + OFF_HHAT);
    uint16_t* What = (uint16_t*)(ws + OFF_WHAT);
    uint16_t* Qhat = (uint16_t*)(ws + OFF_QHAT);
    uint16_t* Khat = (uint16_t*)(ws + OFF_KHAT);
    uint16_t* Vt   = (uint16_t*)(ws + OFF_VT);
    uint16_t* Vhi  = (uint16_t*)(ws + OFF_VHI);
    uint16_t* Vlo  = (uint16_t*)(ws + OFF_VLO);
    float*    sc   = (float*)(ws + OFF_SC);
    uint16_t* Phat = (uint16_t*)(ws + OFF_PHAT);

    pack_inputs<<<dim3(11264), 256, 0, stream>>>(h, Wq, Wk, Wv, Hhat, What);
    gemm_proj2<<<dim3(384), 512, 0, stream>>>(Hhat, What, bq, bk, bv, Qhat, Khat, Vhi, Vlo);
    transpose_v<<<dim3(64, 32, 4), 256, 0, stream>>>(Vhi, Vlo, Vt);
    gemm_scores<<<dim3(256), 512, 0, stream>>>(Qhat, Khat, sc);
    softmax_split<<<dim3(S_, B_), 256, 0, stream>>>(sc, hb, Phat);
    gemm_pv<<<dim3(256), 512, 0, stream>>>(Phat, Vt, out);
}